// Round 11
// baseline (4626.542 us; speedup 1.0000x reference)
//
#include <hip/hip_runtime.h>
#include <hip/hip_bf16.h>

#define HDIM 512
#define BATCH 16
#define TSEQ 600
#define NROW (BATCH*TSEQ)

typedef unsigned short u16;
typedef unsigned long long u64;
typedef __attribute__((ext_vector_type(8))) short short8;   // 8 x bf16 (MFMA A/B frag)
typedef __attribute__((ext_vector_type(4))) float f32x4;    // MFMA C/D frag
typedef __attribute__((ext_vector_type(4))) int i32x4;      // 16 x i8 frag / i32x4 acc

__device__ __forceinline__ u16 f2b(float f){
  unsigned x; __builtin_memcpy(&x, &f, 4);
  x += 0x7fffu + ((x >> 16) & 1u);            // RNE
  return (u16)(x >> 16);
}
__device__ __forceinline__ float b2f(u16 u){
  unsigned x = ((unsigned)u) << 16; float f; __builtin_memcpy(&f, &x, 4); return f;
}

#define LOG2E 1.44269504f
// exp2-form sigmoid/tanh on native v_exp_f32/v_rcp_f32 (~1 ulp, 3x fewer ops than __expf)
__device__ __forceinline__ float fsig(float x){
  return __builtin_amdgcn_rcpf(1.f + __builtin_amdgcn_exp2f(-x*LOG2E));
}
__device__ __forceinline__ float ftanh(float x){
  return 2.f*__builtin_amdgcn_rcpf(1.f + __builtin_amdgcn_exp2f(-2.f*LOG2E*x)) - 1.f;
}

// ---------------- elementwise fp32 -> bf16 ----------------
__global__ void cvt_kernel(const float* __restrict__ in, u16* __restrict__ out, int n4){
  int i = blockIdx.x*blockDim.x + threadIdx.x;
  if (i < n4){
    float4 v = ((const float4*)in)[i];
    ushort4 u; u.x=f2b(v.x); u.y=f2b(v.y); u.z=f2b(v.z); u.w=f2b(v.w);
    ((ushort4*)out)[i] = u;
  }
}

// ---------------- max|w| over 4 equal-size matrices (grid.y selects) ----------------
__global__ void maxabs4_kernel(const float* __restrict__ a, const float* __restrict__ b,
                               const float* __restrict__ c, const float* __restrict__ d,
                               unsigned* __restrict__ outmax, int n){
  const float* p = (blockIdx.y==0)?a:(blockIdx.y==1)?b:(blockIdx.y==2)?c:d;
  float m = 0.f;
  for (int i = blockIdx.x*blockDim.x + threadIdx.x; i < n; i += gridDim.x*blockDim.x)
    m = fmaxf(m, fabsf(p[i]));
  for (int off=32; off>0; off>>=1) m = fmaxf(m, __shfl_down(m, off));
  if ((threadIdx.x & 63) == 0) atomicMax(outmax + blockIdx.y, __float_as_uint(m));
}

// ---------------- fp32 -> i8 quant for 4 matrices (grid.y selects) ----------------
__global__ void quantw4_kernel(const float* __restrict__ a, const float* __restrict__ b,
                               const float* __restrict__ c, const float* __restrict__ d,
                               const unsigned* __restrict__ maxu,
                               signed char* __restrict__ oa, signed char* __restrict__ ob,
                               signed char* __restrict__ oc, signed char* __restrict__ od, int n4){
  int i = blockIdx.x*blockDim.x + threadIdx.x;
  if (i >= n4) return;
  const float* p = (blockIdx.y==0)?a:(blockIdx.y==1)?b:(blockIdx.y==2)?c:d;
  signed char* o = (blockIdx.y==0)?oa:(blockIdx.y==1)?ob:(blockIdx.y==2)?oc:od;
  float s = 127.f / fmaxf(__uint_as_float(maxu[blockIdx.y]), 1e-20f);
  float4 v = ((const float4*)p)[i];
  unsigned x0 = (unsigned)((int)rintf(v.x*s) & 255);
  unsigned x1 = (unsigned)((int)rintf(v.y*s) & 255);
  unsigned x2 = (unsigned)((int)rintf(v.z*s) & 255);
  unsigned x3 = (unsigned)((int)rintf(v.w*s) & 255);
  ((unsigned*)o)[i] = x0 | (x1<<8) | (x2<<16) | (x3<<24);
}

// ---------------- x [16][512][600] fp32 -> xt [b*600+t][512] bf16 ----------------
__global__ __launch_bounds__(256) void transpose_kernel(const float* __restrict__ x, u16* __restrict__ xt){
  __shared__ float tile[32][33];
  int t0 = blockIdx.x*32, h0 = blockIdx.y*32, b = blockIdx.z;
  int li = threadIdx.x & 31, lj = threadIdx.x >> 5;
  for (int j=lj; j<32; j+=8){
    int t = t0 + li;
    tile[j][li] = (t < TSEQ) ? x[((size_t)b*HDIM + h0 + j)*TSEQ + t] : 0.f;
  }
  __syncthreads();
  for (int j=lj; j<32; j+=8){
    int t = t0 + j;
    if (t < TSEQ) xt[((size_t)b*TSEQ + t)*HDIM + h0 + li] = f2b(tile[li][j]);
  }
}

// ---------------- NT GEMM: C[M,N] = A[M,K] * B[N,K]^T + bias, bf16 in, OT out ----------------
template<typename OT>
__global__ __launch_bounds__(256) void gemm_bt(const u16* __restrict__ A, const u16* __restrict__ B,
    const float* __restrict__ bias, OT* __restrict__ C, int M, int N, int K)
{
  __shared__ u16 As[128][40];
  __shared__ u16 Bs[128][40];
  const int m0 = blockIdx.x*128, n0 = blockIdx.y*128;
  const int tid = threadIdx.x, lane = tid & 63;
  const int wr = ((tid>>6)&1)*64, wc = ((tid>>6)>>1)*64;
  const int srow = tid>>2, scol = (tid&3)*8;
  f32x4 acc[4][4] = {};
  for (int k0=0; k0<K; k0+=32){
    uint4 a0 = *(const uint4*)(A + (size_t)(m0+srow)*K    + k0 + scol);
    uint4 a1 = *(const uint4*)(A + (size_t)(m0+srow+64)*K + k0 + scol);
    uint4 b0 = *(const uint4*)(B + (size_t)(n0+srow)*K    + k0 + scol);
    uint4 b1 = *(const uint4*)(B + (size_t)(n0+srow+64)*K + k0 + scol);
    __syncthreads();
    *(uint4*)&As[srow][scol]    = a0;
    *(uint4*)&As[srow+64][scol] = a1;
    *(uint4*)&Bs[srow][scol]    = b0;
    *(uint4*)&Bs[srow+64][scol] = b1;
    __syncthreads();
    short8 af[4], bfr[4];
#pragma unroll
    for (int i=0;i<4;i++) af[i]  = *(const short8*)&As[wr + i*16 + (lane&15)][(lane>>4)*8];
#pragma unroll
    for (int i=0;i<4;i++) bfr[i] = *(const short8*)&Bs[wc + i*16 + (lane&15)][(lane>>4)*8];
#pragma unroll
    for (int i=0;i<4;i++)
#pragma unroll
      for (int j=0;j<4;j++)
        acc[i][j] = __builtin_amdgcn_mfma_f32_16x16x32_bf16(af[i], bfr[j], acc[i][j], 0,0,0);
  }
#pragma unroll
  for (int i=0;i<4;i++)
#pragma unroll
    for (int j=0;j<4;j++){
      int row = m0 + wr + i*16 + (lane>>4)*4;
      int col = n0 + wc + j*16 + (lane&15);
      float bv = bias ? bias[col] : 0.f;
#pragma unroll
      for (int r=0;r<4;r++){
        float v = acc[i][j][r] + bv;
        if (sizeof(OT) == 2) C[(size_t)(row+r)*N + col] = (OT)f2b(v);
        else                 C[(size_t)(row+r)*N + col] = (OT)v;
      }
    }
}

// ---------------- persistent bidirectional LSTM recurrence, v11 ----------------
// R10 protocol (self-validating atoms {tag=step | 4 x i8 h} at the IC, per-wave
// tag hints on 32 hot lines, no drains) + ONE change: the consumer's batched
// 4-atom read is issued SPECULATIVELY BEFORE the tag spin, so its IC RTT
// overlaps detection. The spin's first vmcnt(0) drains the in-flight atom
// reads (free: the tag isn't visible that early anyway); by spin exit the
// values are in registers. Per-atom validation (already required: producer's
// atom and tag stores can complete out of order) catches the race where the
// speculative read beat the producer -- then fall back to R10's re-read loop.
// Overwrite-safety unchanged (inductive via the post-staging barrier).
__global__ __launch_bounds__(512, 1) void lstm_rec11(
    const u16* __restrict__ xp_f, const u16* __restrict__ xp_b,   // [NROW][2048] bf16
    const signed char* __restrict__ w8_f, const signed char* __restrict__ w8_b, // [2048][512] i8
    const unsigned* __restrict__ maxu,  // maxabs(w) fwd, bwd (uint-as-float)
    u16* __restrict__ h_out,            // [NROW][1024] bf16
    u64* __restrict__ dpl,              // [2 dir][2 par][2048] tagged atoms (zeroed)
    unsigned* __restrict__ tags)        // [2 dir][2 par][32 waves] x 16B stride (zeroed)
{
  const int bi = blockIdx.x, rem = bi & 7;
  if (rem > 1) return;
  const int dir = rem, wid = bi >> 3;           // wid in 0..3: pos slice [wid*128, +128)
  const int tid = threadIdx.x, lane = tid & 63, w = tid >> 6;  // 8 waves; wave owns 16 pos
  const int l15 = lane & 15, lq = lane >> 4;
  const int P = wid*128 + w*16;

  const u16* xp = dir ? xp_b : xp_f;
  const signed char* w8 = dir ? w8_b : w8_f;
  const float mx = __uint_as_float(maxu[dir]);
  const float sA = mx / (127.f*127.f);

  __shared__ __align__(16) signed char hL[2][16][528];   // parity-double-buffered h plane

  // w_hh slice -> registers as i8 A-frags: wf[gate][k-iter], A[m=l15][k=lq*16+j]
  i32x4 wf[4][8];
#pragma unroll
  for (int g=0; g<4; ++g)
#pragma unroll
    for (int kk=0; kk<8; ++kk)
      wf[g][kk] = *(const i32x4*)(w8 + (size_t)(g*512 + P + l15)*512 + kk*64 + lq*16);

  u64* pl = dpl + (size_t)dir*(2*2048);
  const int mychunk = l15*128 + (P >> 2) + lq;     // producer atom index
  // consumer: thread (cb, cp16) reads the 4 consecutive atoms of producer wave cp16
  const int cb = tid >> 5, cp16 = tid & 31;
  const int cP = (cp16 >> 3)*128 + (cp16 & 7)*16;  // that wave's position base
  const int coff = cb*128 + (cP >> 2);             // first of its 4 atoms for batch cb

  float c[4] = {0.f,0.f,0.f,0.f};
  const int t0 = dir ? (TSEQ-1) : 0, ts = dir ? -1 : 1;

  for (int s=0; s<TSEQ; ++s){
    const int t = t0 + s*ts;
    const int par = s & 1;

    // xp prefetch (plain loads; complete while we wait)
    ushort4 xq[4];
    {
      const u16* px = xp + ((size_t)(l15*TSEQ + t))*2048 + P + lq*4;
#pragma unroll
      for (int g=0; g<4; ++g) xq[g] = *(const ushort4*)(px + g*512);
    }

    // stage h plane: SPECULATIVE batched 4-atom read overlapped with tag spin
    {
      const u64* q = pl + (size_t)par*2048 + coff;
      u64 v[4];
#pragma unroll
      for (int i=0;i<4;i++)
        v[i] = __hip_atomic_load(q+i, __ATOMIC_RELAXED, __HIP_MEMORY_SCOPE_AGENT);
      // tag spin: atoms' IC flight overlaps this wait
      {
        const unsigned* tp = tags + ((dir*2 + par)*32 + cp16)*4;
        while ((int)__hip_atomic_load(tp, __ATOMIC_RELAXED, __HIP_MEMORY_SCOPE_AGENT) < s) {}
      }
      // validate; re-read only atoms the speculation missed (rare)
      for (;;){
        bool ok = true;
#pragma unroll
        for (int i=0;i<4;i++) ok &= ((unsigned)(v[i] >> 32) == (unsigned)s);
        if (ok) break;
#pragma unroll
        for (int i=0;i<4;i++)
          if ((unsigned)(v[i] >> 32) != (unsigned)s)
            v[i] = __hip_atomic_load(q+i, __ATOMIC_RELAXED, __HIP_MEMORY_SCOPE_AGENT);
      }
      u64 lo = (u64)(unsigned)v[0] | ((u64)(unsigned)v[1] << 32);
      u64 hi = (u64)(unsigned)v[2] | ((u64)(unsigned)v[3] << 32);
      *(u64*)&hL[par][cb][cP]     = lo;
      *(u64*)&hL[par][cb][cP + 8] = hi;
    }
    __syncthreads();

    // G = W x h^T : A = weights (regs), B = h plane (LDS)
    i32x4 acc[4] = {};
#pragma unroll
    for (int kk=0; kk<8; ++kk){
      i32x4 b1 = *(const i32x4*)(&hL[par][l15][0] + kk*64 + lq*16);
#pragma unroll
      for (int g=0; g<4; ++g)
        acc[g] = __builtin_amdgcn_mfma_i32_16x16x64_i8(wf[g][kk], b1, acc[g], 0, 0, 0);
    }

    // gates: lane holds batch=l15, pos = P + lq*4 + r
    unsigned pk1 = 0; float hhv[4];
#pragma unroll
    for (int r=0; r<4; ++r){
      float pre[4];
#pragma unroll
      for (int g=0; g<4; ++g)
        pre[g] = b2f(((const u16*)&xq[g])[r]) + sA*(float)acc[g][r];
      float iv = fsig(pre[0]);
      float fv = fsig(pre[1]);
      float gv = ftanh(pre[2]);
      float ov = fsig(pre[3]);
      float cc = fv*c[r] + iv*gv; c[r] = cc;
      float hh = ov*ftanh(cc);
      hhv[r] = hh;
      int d1i = (int)rintf(hh*127.f);
      pk1 |= (unsigned)(d1i & 255) << (8*r);
    }
    // publish: self-validating atom, then tag hint -- no drains
    if (s < TSEQ-1){
      u64 chunk = ((u64)(unsigned)(s+1) << 32) | (u64)pk1;
      __hip_atomic_store(pl + (size_t)(par^1)*2048 + mychunk, chunk,
                         __ATOMIC_RELAXED, __HIP_MEMORY_SCOPE_AGENT);
      if (lane == 0){
        unsigned* tg = tags + ((dir*2 + (par^1))*32 + wid*8 + w)*4;
        __hip_atomic_store(tg, (unsigned)(s+1), __ATOMIC_RELAXED, __HIP_MEMORY_SCOPE_AGENT);
      }
    }
    // off-path h_out store (after publish)
    ushort4 hu;
#pragma unroll
    for (int r=0; r<4; ++r) ((u16*)&hu)[r] = f2b(hhv[r]);
    *(ushort4*)(h_out + ((size_t)(l15*TSEQ + t))*1024 + dir*512 + P + lq*4) = hu;
  }
}

// ---------------- fused LayerNorm + ReLU over last dim (512) ----------------
__global__ __launch_bounds__(256) void ln_relu_kernel(const float* __restrict__ in,
    const float* __restrict__ gw, const float* __restrict__ gb, float* __restrict__ out)
{
  __shared__ float rs[4], rss[4];
  const int row = blockIdx.x;
  const float* p = in + (size_t)row*HDIM;
  float v0 = p[threadIdx.x], v1 = p[threadIdx.x + 256];
  float s = v0 + v1, ss = v0*v0 + v1*v1;
  for (int off=32; off>0; off>>=1){
    s  += __shfl_down(s, off);
    ss += __shfl_down(ss, off);
  }
  if ((threadIdx.x & 63) == 0){ rs[threadIdx.x>>6] = s; rss[threadIdx.x>>6] = ss; }
  __syncthreads();
  float st  = rs[0]+rs[1]+rs[2]+rs[3];
  float sst = rss[0]+rss[1]+rss[2]+rss[3];
  float mu  = st * (1.f/HDIM);
  float var = sst * (1.f/HDIM) - mu*mu;
  float rstd = rsqrtf(var + 1e-5f);
  int c0 = threadIdx.x, c1 = threadIdx.x + 256;
  float y0 = (v0 - mu)*rstd*gw[c0] + gb[c0];
  float y1 = (v1 - mu)*rstd*gw[c1] + gb[c1];
  out[(size_t)row*HDIM + c0] = fmaxf(y0, 0.f);
  out[(size_t)row*HDIM + c1] = fmaxf(y1, 0.f);
}

extern "C" void kernel_launch(void* const* d_in, const int* in_sizes, int n_in,
                              void* d_out, int out_size, void* d_ws, size_t ws_size,
                              hipStream_t stream)
{
  const float* x        = (const float*)d_in[0];
  const float* wih_l0f  = (const float*)d_in[1];
  const float* whh_l0f  = (const float*)d_in[2];
  const float* b_l0f    = (const float*)d_in[3];
  const float* wih_l0b  = (const float*)d_in[4];
  const float* whh_l0b  = (const float*)d_in[5];
  const float* b_l0b    = (const float*)d_in[6];
  const float* wih_l1f  = (const float*)d_in[7];
  const float* whh_l1f  = (const float*)d_in[8];
  const float* b_l1f    = (const float*)d_in[9];
  const float* wih_l1b  = (const float*)d_in[10];
  const float* whh_l1b  = (const float*)d_in[11];
  const float* b_l1b    = (const float*)d_in[12];
  const float* fc_w     = (const float*)d_in[13];
  const float* fc_b     = (const float*)d_in[14];
  const float* ln_w     = (const float*)d_in[15];
  const float* ln_b     = (const float*)d_in[16];
  float* outp = (float*)d_out;

  char* base = (char*)d_ws;
  size_t off = 0;
  auto alloc = [&](size_t bytes)->char*{ char* p = base + off; off += (bytes + 255) & ~(size_t)255; return p; };

  // ---- zeroed region (re-zeroed every launch: harness poisons ws) ----
  unsigned* maxu = (unsigned*)alloc(256);                  // [0..3]: l0f,l0b,l1f,l1b
  u64* dpl0 = (u64*)alloc((size_t)2*2*2048*8);             // atom tag 0 == valid h=0 for s=0
  u64* dpl1 = (u64*)alloc((size_t)2*2*2048*8);
  unsigned* tags0 = (unsigned*)alloc((size_t)2*2*32*16);
  unsigned* tags1 = (unsigned*)alloc((size_t)2*2*32*16);
  size_t zero_bytes = off;
  // ---- scratch ----
  signed char* w8_l0f = (signed char*)alloc((size_t)2048*512);
  signed char* w8_l0b = (signed char*)alloc((size_t)2048*512);
  signed char* w8_l1f = (signed char*)alloc((size_t)2048*512);
  signed char* w8_l1b = (signed char*)alloc((size_t)2048*512);
  u16* xt     = (u16*)alloc((size_t)NROW*512*2);
  u16* wb_l0f = (u16*)alloc((size_t)2048*512*2);
  u16* wb_l0b = (u16*)alloc((size_t)2048*512*2);
  u16* wb_l1f = (u16*)alloc((size_t)2048*1024*2);
  u16* wb_l1b = (u16*)alloc((size_t)2048*1024*2);
  u16* wb_fc  = (u16*)alloc((size_t)512*1024*2);
  u16* h0     = (u16*)alloc((size_t)NROW*1024*2);
  u16* h1     = (u16*)alloc((size_t)NROW*1024*2);
  u16* xpf    = (u16*)alloc((size_t)NROW*2048*2);
  u16* xpb    = (u16*)alloc((size_t)NROW*2048*2);
  float* fco  = (float*)alloc((size_t)NROW*512*4);
  (void)ws_size; (void)in_sizes; (void)n_in; (void)out_size;

  hipMemsetAsync(d_ws, 0, zero_bytes, stream);

  auto cvt = [&](const float* in, u16* out, int n){
    int n4 = n/4;
    cvt_kernel<<<dim3((n4+255)/256), 256, 0, stream>>>(in, out, n4);
  };
  cvt(wih_l0f, wb_l0f, 2048*512);
  cvt(wih_l0b, wb_l0b, 2048*512);
  cvt(wih_l1f, wb_l1f, 2048*1024);
  cvt(wih_l1b, wb_l1b, 2048*1024);
  cvt(fc_w,    wb_fc,  512*1024);

  // w_hh i8 quant (global scale per matrix) -- 4 matrices per launch
  maxabs4_kernel<<<dim3(64,4), 256, 0, stream>>>(whh_l0f, whh_l0b, whh_l1f, whh_l1b, maxu, 2048*512);
  quantw4_kernel<<<dim3((2048*512/4+255)/256,4), 256, 0, stream>>>(
      whh_l0f, whh_l0b, whh_l1f, whh_l1b, maxu, w8_l0f, w8_l0b, w8_l1f, w8_l1b, 2048*512/4);

  transpose_kernel<<<dim3(19,16,16), 256, 0, stream>>>(x, xt);

  // layer 0: input projections then recurrence
  gemm_bt<u16><<<dim3(75,16), 256, 0, stream>>>(xt, wb_l0f, b_l0f, xpf, NROW, 2048, 512);
  gemm_bt<u16><<<dim3(75,16), 256, 0, stream>>>(xt, wb_l0b, b_l0b, xpb, NROW, 2048, 512);
  lstm_rec11<<<dim3(32), 512, 0, stream>>>(xpf, xpb, w8_l0f, w8_l0b, maxu+0, h0, dpl0, tags0);

  // layer 1
  gemm_bt<u16><<<dim3(75,16), 256, 0, stream>>>(h0, wb_l1f, b_l1f, xpf, NROW, 2048, 1024);
  gemm_bt<u16><<<dim3(75,16), 256, 0, stream>>>(h0, wb_l1b, b_l1b, xpb, NROW, 2048, 1024);
  lstm_rec11<<<dim3(32), 512, 0, stream>>>(xpf, xpb, w8_l1f, w8_l1b, maxu+2, h1, dpl1, tags1);

  // FC + LayerNorm + ReLU
  gemm_bt<float><<<dim3(75,4), 256, 0, stream>>>(h1, wb_fc, fc_b, fco, NROW, 512, 1024);
  ln_relu_kernel<<<dim3(NROW), 256, 0, stream>>>(fco, ln_w, ln_b, outp);
}

// Round 12
// 4001.287 us; speedup vs baseline: 1.1563x; 1.1563x over previous
//
#include <hip/hip_runtime.h>
#include <hip/hip_bf16.h>

#define HDIM 512
#define BATCH 16
#define TSEQ 600
#define NROW (BATCH*TSEQ)

typedef unsigned short u16;
typedef unsigned long long u64;
typedef __attribute__((ext_vector_type(8))) short short8;   // 8 x bf16 (MFMA A/B frag)
typedef __attribute__((ext_vector_type(4))) float f32x4;    // MFMA C/D frag
typedef __attribute__((ext_vector_type(4))) int i32x4;      // 16 x i8 frag / i32x4 acc

__device__ __forceinline__ u16 f2b(float f){
  unsigned x; __builtin_memcpy(&x, &f, 4);
  x += 0x7fffu + ((x >> 16) & 1u);            // RNE
  return (u16)(x >> 16);
}
__device__ __forceinline__ float b2f(u16 u){
  unsigned x = ((unsigned)u) << 16; float f; __builtin_memcpy(&f, &x, 4); return f;
}

#define LOG2E 1.44269504f
__device__ __forceinline__ float fsig(float x){
  return __builtin_amdgcn_rcpf(1.f + __builtin_amdgcn_exp2f(-x*LOG2E));
}
__device__ __forceinline__ float ftanh(float x){
  return 2.f*__builtin_amdgcn_rcpf(1.f + __builtin_amdgcn_exp2f(-2.f*LOG2E*x)) - 1.f;
}

// ---------------- elementwise fp32 -> bf16 ----------------
__global__ void cvt_kernel(const float* __restrict__ in, u16* __restrict__ out, int n4){
  int i = blockIdx.x*blockDim.x + threadIdx.x;
  if (i < n4){
    float4 v = ((const float4*)in)[i];
    ushort4 u; u.x=f2b(v.x); u.y=f2b(v.y); u.z=f2b(v.z); u.w=f2b(v.w);
    ((ushort4*)out)[i] = u;
  }
}

// ---------------- max|w| over 4 equal-size matrices (grid.y selects) ----------------
__global__ void maxabs4_kernel(const float* __restrict__ a, const float* __restrict__ b,
                               const float* __restrict__ c, const float* __restrict__ d,
                               unsigned* __restrict__ outmax, int n){
  const float* p = (blockIdx.y==0)?a:(blockIdx.y==1)?b:(blockIdx.y==2)?c:d;
  float m = 0.f;
  for (int i = blockIdx.x*blockDim.x + threadIdx.x; i < n; i += gridDim.x*blockDim.x)
    m = fmaxf(m, fabsf(p[i]));
  for (int off=32; off>0; off>>=1) m = fmaxf(m, __shfl_down(m, off));
  if ((threadIdx.x & 63) == 0) atomicMax(outmax + blockIdx.y, __float_as_uint(m));
}

// ---------------- fp32 -> i8 quant for 4 matrices (grid.y selects) ----------------
__global__ void quantw4_kernel(const float* __restrict__ a, const float* __restrict__ b,
                               const float* __restrict__ c, const float* __restrict__ d,
                               const unsigned* __restrict__ maxu,
                               signed char* __restrict__ oa, signed char* __restrict__ ob,
                               signed char* __restrict__ oc, signed char* __restrict__ od, int n4){
  int i = blockIdx.x*blockDim.x + threadIdx.x;
  if (i >= n4) return;
  const float* p = (blockIdx.y==0)?a:(blockIdx.y==1)?b:(blockIdx.y==2)?c:d;
  signed char* o = (blockIdx.y==0)?oa:(blockIdx.y==1)?ob:(blockIdx.y==2)?oc:od;
  float s = 127.f / fmaxf(__uint_as_float(maxu[blockIdx.y]), 1e-20f);
  float4 v = ((const float4*)p)[i];
  unsigned x0 = (unsigned)((int)rintf(v.x*s) & 255);
  unsigned x1 = (unsigned)((int)rintf(v.y*s) & 255);
  unsigned x2 = (unsigned)((int)rintf(v.z*s) & 255);
  unsigned x3 = (unsigned)((int)rintf(v.w*s) & 255);
  ((unsigned*)o)[i] = x0 | (x1<<8) | (x2<<16) | (x3<<24);
}

// ---------------- x [16][512][600] fp32 -> xt [b*600+t][512] bf16 ----------------
__global__ __launch_bounds__(256) void transpose_kernel(const float* __restrict__ x, u16* __restrict__ xt){
  __shared__ float tile[32][33];
  int t0 = blockIdx.x*32, h0 = blockIdx.y*32, b = blockIdx.z;
  int li = threadIdx.x & 31, lj = threadIdx.x >> 5;
  for (int j=lj; j<32; j+=8){
    int t = t0 + li;
    tile[j][li] = (t < TSEQ) ? x[((size_t)b*HDIM + h0 + j)*TSEQ + t] : 0.f;
  }
  __syncthreads();
  for (int j=lj; j<32; j+=8){
    int t = t0 + j;
    if (t < TSEQ) xt[((size_t)b*TSEQ + t)*HDIM + h0 + li] = f2b(tile[li][j]);
  }
}

// ---------------- NT GEMM: C[M,N] = A[M,K] * B[N,K]^T + bias, bf16 in, OT out ----------------
template<typename OT>
__global__ __launch_bounds__(256) void gemm_bt(const u16* __restrict__ A, const u16* __restrict__ B,
    const float* __restrict__ bias, OT* __restrict__ C, int M, int N, int K)
{
  __shared__ u16 As[128][40];
  __shared__ u16 Bs[128][40];
  const int m0 = blockIdx.x*128, n0 = blockIdx.y*128;
  const int tid = threadIdx.x, lane = tid & 63;
  const int wr = ((tid>>6)&1)*64, wc = ((tid>>6)>>1)*64;
  const int srow = tid>>2, scol = (tid&3)*8;
  f32x4 acc[4][4] = {};
  for (int k0=0; k0<K; k0+=32){
    uint4 a0 = *(const uint4*)(A + (size_t)(m0+srow)*K    + k0 + scol);
    uint4 a1 = *(const uint4*)(A + (size_t)(m0+srow+64)*K + k0 + scol);
    uint4 b0 = *(const uint4*)(B + (size_t)(n0+srow)*K    + k0 + scol);
    uint4 b1 = *(const uint4*)(B + (size_t)(n0+srow+64)*K + k0 + scol);
    __syncthreads();
    *(uint4*)&As[srow][scol]    = a0;
    *(uint4*)&As[srow+64][scol] = a1;
    *(uint4*)&Bs[srow][scol]    = b0;
    *(uint4*)&Bs[srow+64][scol] = b1;
    __syncthreads();
    short8 af[4], bfr[4];
#pragma unroll
    for (int i=0;i<4;i++) af[i]  = *(const short8*)&As[wr + i*16 + (lane&15)][(lane>>4)*8];
#pragma unroll
    for (int i=0;i<4;i++) bfr[i] = *(const short8*)&Bs[wc + i*16 + (lane&15)][(lane>>4)*8];
#pragma unroll
    for (int i=0;i<4;i++)
#pragma unroll
      for (int j=0;j<4;j++)
        acc[i][j] = __builtin_amdgcn_mfma_f32_16x16x32_bf16(af[i], bfr[j], acc[i][j], 0,0,0);
  }
#pragma unroll
  for (int i=0;i<4;i++)
#pragma unroll
    for (int j=0;j<4;j++){
      int row = m0 + wr + i*16 + (lane>>4)*4;
      int col = n0 + wc + j*16 + (lane&15);
      float bv = bias ? bias[col] : 0.f;
#pragma unroll
      for (int r=0;r<4;r++){
        float v = acc[i][j][r] + bv;
        if (sizeof(OT) == 2) C[(size_t)(row+r)*N + col] = (OT)f2b(v);
        else                 C[(size_t)(row+r)*N + col] = (OT)v;
      }
    }
}

// ---------------- persistent bidirectional LSTM recurrence, v12 ----------------
// R10 protocol (self-validating atoms {tag=step | 4 x i8 h} at the IC, tag
// hints, read-after-detect -- R11 proved speculative pre-detect reads only
// add traffic) + SPLIT-K OVERLAP: each WG's own 128-position K-quarter of
// next step's MFMA depends only on LOCALLY produced h, so own h goes
// straight to LDS (never through the IC for self-consumption) and phase-1
// MFMA (own 2 of 8 kk-iters) runs BEFORE foreign-atom detection -- hiding
// gates+LDS+barrier+phase1 under the producer->consumer IC flight. Weight
// frags loaded in rotated kk order ((wid*2+j)&7) so phase1 is always j=0,1.
// Consumers skip their own WG's 8 producer waves. Overwrite-safety induction
// unchanged (every WG pair still exchanges atoms; chain passes through
// publish -> barrier A -> prior reads).
__global__ __launch_bounds__(512, 1) void lstm_rec12(
    const u16* __restrict__ xp_f, const u16* __restrict__ xp_b,   // [NROW][2048] bf16
    const signed char* __restrict__ w8_f, const signed char* __restrict__ w8_b, // [2048][512] i8
    const unsigned* __restrict__ maxu,  // maxabs(w) fwd, bwd (uint-as-float)
    u16* __restrict__ h_out,            // [NROW][1024] bf16
    u64* __restrict__ dpl,              // [2 dir][2 par][2048] tagged atoms (zeroed)
    unsigned* __restrict__ tags)        // [2 dir][2 par][32 waves] x 16B stride (zeroed)
{
  const int bi = blockIdx.x, rem = bi & 7;
  if (rem > 1) return;
  const int dir = rem, wid = bi >> 3;           // wid in 0..3: pos slice [wid*128, +128)
  const int tid = threadIdx.x, lane = tid & 63, w = tid >> 6;  // 8 waves; wave owns 16 pos
  const int l15 = lane & 15, lq = lane >> 4;
  const int P = wid*128 + w*16;

  const u16* xp = dir ? xp_b : xp_f;
  const signed char* w8 = dir ? w8_b : w8_f;
  const float mx = __uint_as_float(maxu[dir]);
  const float sA = mx / (127.f*127.f);

  __shared__ __align__(16) signed char hL[2][16][528];   // parity-double-buffered h plane

  // w_hh slice -> regs as i8 A-frags in ROTATED kk order: j=0,1 are this WG's
  // own K-quarter (kkphys = (wid*2+j)&7), so phase1 needs no branching.
  i32x4 wf[4][8];
#pragma unroll
  for (int g=0; g<4; ++g)
#pragma unroll
    for (int j=0; j<8; ++j){
      const int kkp = (wid*2 + j) & 7;
      wf[g][j] = *(const i32x4*)(w8 + (size_t)(g*512 + P + l15)*512 + kkp*64 + lq*16);
    }

  u64* pl = dpl + (size_t)dir*(2*2048);
  const int mychunk = l15*128 + (P >> 2) + lq;     // producer atom index
  // consumer: thread (cb, cp16) reads the 4 consecutive atoms of producer wave cp16
  const int cb = tid >> 5, cp16 = tid & 31;
  const int cwid = cp16 >> 3;                      // producer wave's WG
  const int cP = cwid*128 + (cp16 & 7)*16;         // that wave's position base
  const int coff = cb*128 + (cP >> 2);             // first of its 4 atoms for batch cb
  const bool foreign = (cwid != wid);              // own WG's data arrives via LDS

  // zero both LDS parities (h_{-1} = 0)
  for (int i = tid; i < 2*16*528/4; i += 512) ((unsigned*)hL)[i] = 0u;
  __syncthreads();

  float c[4] = {0.f,0.f,0.f,0.f};
  const int t0 = dir ? (TSEQ-1) : 0, ts = dir ? -1 : 1;

  for (int s=0; s<TSEQ; ++s){
    const int t = t0 + s*ts;
    const int par = s & 1;

    // xp prefetch (plain loads; complete while we compute/wait)
    ushort4 xq[4];
    {
      const u16* px = xp + ((size_t)(l15*TSEQ + t))*2048 + P + lq*4;
#pragma unroll
      for (int g=0; g<4; ++g) xq[g] = *(const ushort4*)(px + g*512);
    }

    // phase 1 MFMA: own K-quarter (local h, already in LDS) -- no IC dependency
    i32x4 acc[4] = {};
#pragma unroll
    for (int j=0; j<2; ++j){
      const int kkp = (wid*2 + j) & 7;
      i32x4 b1 = *(const i32x4*)(&hL[par][l15][0] + kkp*64 + lq*16);
#pragma unroll
      for (int g=0; g<4; ++g)
        acc[g] = __builtin_amdgcn_mfma_i32_16x16x64_i8(wf[g][j], b1, acc[g], 0, 0, 0);
    }

    // stage foreign h quarters: tag spin -> batched 4-atom read -> validate
    if (foreign){
      const unsigned* tp = tags + ((dir*2 + par)*32 + cp16)*4;
      while ((int)__hip_atomic_load(tp, __ATOMIC_RELAXED, __HIP_MEMORY_SCOPE_AGENT) < s) {}
      const u64* q = pl + (size_t)par*2048 + coff;
      u64 v[4];
#pragma unroll
      for (int i=0;i<4;i++)
        v[i] = __hip_atomic_load(q+i, __ATOMIC_RELAXED, __HIP_MEMORY_SCOPE_AGENT);
      for (;;){
        bool ok = true;
#pragma unroll
        for (int i=0;i<4;i++) ok &= ((unsigned)(v[i] >> 32) == (unsigned)s);
        if (ok) break;
#pragma unroll
        for (int i=0;i<4;i++)
          if ((unsigned)(v[i] >> 32) != (unsigned)s)
            v[i] = __hip_atomic_load(q+i, __ATOMIC_RELAXED, __HIP_MEMORY_SCOPE_AGENT);
      }
      u64 lo = (u64)(unsigned)v[0] | ((u64)(unsigned)v[1] << 32);
      u64 hi = (u64)(unsigned)v[2] | ((u64)(unsigned)v[3] << 32);
      *(u64*)&hL[par][cb][cP]     = lo;
      *(u64*)&hL[par][cb][cP + 8] = hi;
    }
    __syncthreads();     // barrier A: foreign quarters staged

    // phase 2 MFMA: remaining 6 kk over foreign quarters
#pragma unroll
    for (int j=2; j<8; ++j){
      const int kkp = (wid*2 + j) & 7;
      i32x4 b1 = *(const i32x4*)(&hL[par][l15][0] + kkp*64 + lq*16);
#pragma unroll
      for (int g=0; g<4; ++g)
        acc[g] = __builtin_amdgcn_mfma_i32_16x16x64_i8(wf[g][j], b1, acc[g], 0, 0, 0);
    }

    // gates: lane holds batch=l15, pos = P + lq*4 + r
    unsigned pk1 = 0; float hhv[4];
#pragma unroll
    for (int r=0; r<4; ++r){
      float pre[4];
#pragma unroll
      for (int g=0; g<4; ++g)
        pre[g] = b2f(((const u16*)&xq[g])[r]) + sA*(float)acc[g][r];
      float iv = fsig(pre[0]);
      float fv = fsig(pre[1]);
      float gv = ftanh(pre[2]);
      float ov = fsig(pre[3]);
      float cc = fv*c[r] + iv*gv; c[r] = cc;
      float hh = ov*ftanh(cc);
      hhv[r] = hh;
      int d1i = (int)rintf(hh*127.f);
      pk1 |= (unsigned)(d1i & 255) << (8*r);
    }
    // publish to the ring FIRST (IC flight overlaps our LDS/h_out/barrier/phase1)
    if (s < TSEQ-1){
      u64 chunk = ((u64)(unsigned)(s+1) << 32) | (u64)pk1;
      __hip_atomic_store(pl + (size_t)(par^1)*2048 + mychunk, chunk,
                         __ATOMIC_RELAXED, __HIP_MEMORY_SCOPE_AGENT);
      if (lane == 0){
        unsigned* tg = tags + ((dir*2 + (par^1))*32 + wid*8 + w)*4;
        __hip_atomic_store(tg, (unsigned)(s+1), __ATOMIC_RELAXED, __HIP_MEMORY_SCOPE_AGENT);
      }
    }
    // own quarter straight to LDS (self-consumption skips the IC entirely)
    *(unsigned*)&hL[par^1][l15][P + lq*4] = pk1;
    // off-path h_out store
    ushort4 hu;
#pragma unroll
    for (int r=0; r<4; ++r) ((u16*)&hu)[r] = f2b(hhv[r]);
    *(ushort4*)(h_out + ((size_t)(l15*TSEQ + t))*1024 + dir*512 + P + lq*4) = hu;
    __syncthreads();     // barrier B: own-quarter LDS writes visible for next phase1
  }
}

// ---------------- fused LayerNorm + ReLU over last dim (512) ----------------
__global__ __launch_bounds__(256) void ln_relu_kernel(const float* __restrict__ in,
    const float* __restrict__ gw, const float* __restrict__ gb, float* __restrict__ out)
{
  __shared__ float rs[4], rss[4];
  const int row = blockIdx.x;
  const float* p = in + (size_t)row*HDIM;
  float v0 = p[threadIdx.x], v1 = p[threadIdx.x + 256];
  float s = v0 + v1, ss = v0*v0 + v1*v1;
  for (int off=32; off>0; off>>=1){
    s  += __shfl_down(s, off);
    ss += __shfl_down(ss, off);
  }
  if ((threadIdx.x & 63) == 0){ rs[threadIdx.x>>6] = s; rss[threadIdx.x>>6] = ss; }
  __syncthreads();
  float st  = rs[0]+rs[1]+rs[2]+rs[3];
  float sst = rss[0]+rss[1]+rss[2]+rss[3];
  float mu  = st * (1.f/HDIM);
  float var = sst * (1.f/HDIM) - mu*mu;
  float rstd = rsqrtf(var + 1e-5f);
  int c0 = threadIdx.x, c1 = threadIdx.x + 256;
  float y0 = (v0 - mu)*rstd*gw[c0] + gb[c0];
  float y1 = (v1 - mu)*rstd*gw[c1] + gb[c1];
  out[(size_t)row*HDIM + c0] = fmaxf(y0, 0.f);
  out[(size_t)row*HDIM + c1] = fmaxf(y1, 0.f);
}

extern "C" void kernel_launch(void* const* d_in, const int* in_sizes, int n_in,
                              void* d_out, int out_size, void* d_ws, size_t ws_size,
                              hipStream_t stream)
{
  const float* x        = (const float*)d_in[0];
  const float* wih_l0f  = (const float*)d_in[1];
  const float* whh_l0f  = (const float*)d_in[2];
  const float* b_l0f    = (const float*)d_in[3];
  const float* wih_l0b  = (const float*)d_in[4];
  const float* whh_l0b  = (const float*)d_in[5];
  const float* b_l0b    = (const float*)d_in[6];
  const float* wih_l1f  = (const float*)d_in[7];
  const float* whh_l1f  = (const float*)d_in[8];
  const float* b_l1f    = (const float*)d_in[9];
  const float* wih_l1b  = (const float*)d_in[10];
  const float* whh_l1b  = (const float*)d_in[11];
  const float* b_l1b    = (const float*)d_in[12];
  const float* fc_w     = (const float*)d_in[13];
  const float* fc_b     = (const float*)d_in[14];
  const float* ln_w     = (const float*)d_in[15];
  const float* ln_b     = (const float*)d_in[16];
  float* outp = (float*)d_out;

  char* base = (char*)d_ws;
  size_t off = 0;
  auto alloc = [&](size_t bytes)->char*{ char* p = base + off; off += (bytes + 255) & ~(size_t)255; return p; };

  // ---- zeroed region (re-zeroed every launch: harness poisons ws) ----
  unsigned* maxu = (unsigned*)alloc(256);                  // [0..3]: l0f,l0b,l1f,l1b
  u64* dpl0 = (u64*)alloc((size_t)2*2*2048*8);             // atom tag 0 == valid h=0 for s=0
  u64* dpl1 = (u64*)alloc((size_t)2*2*2048*8);
  unsigned* tags0 = (unsigned*)alloc((size_t)2*2*32*16);
  unsigned* tags1 = (unsigned*)alloc((size_t)2*2*32*16);
  size_t zero_bytes = off;
  // ---- scratch ----
  signed char* w8_l0f = (signed char*)alloc((size_t)2048*512);
  signed char* w8_l0b = (signed char*)alloc((size_t)2048*512);
  signed char* w8_l1f = (signed char*)alloc((size_t)2048*512);
  signed char* w8_l1b = (signed char*)alloc((size_t)2048*512);
  u16* xt     = (u16*)alloc((size_t)NROW*512*2);
  u16* wb_l0f = (u16*)alloc((size_t)2048*512*2);
  u16* wb_l0b = (u16*)alloc((size_t)2048*512*2);
  u16* wb_l1f = (u16*)alloc((size_t)2048*1024*2);
  u16* wb_l1b = (u16*)alloc((size_t)2048*1024*2);
  u16* wb_fc  = (u16*)alloc((size_t)512*1024*2);
  u16* h0     = (u16*)alloc((size_t)NROW*1024*2);
  u16* h1     = (u16*)alloc((size_t)NROW*1024*2);
  u16* xpf    = (u16*)alloc((size_t)NROW*2048*2);
  u16* xpb    = (u16*)alloc((size_t)NROW*2048*2);
  float* fco  = (float*)alloc((size_t)NROW*512*4);
  (void)ws_size; (void)in_sizes; (void)n_in; (void)out_size;

  hipMemsetAsync(d_ws, 0, zero_bytes, stream);

  auto cvt = [&](const float* in, u16* out, int n){
    int n4 = n/4;
    cvt_kernel<<<dim3((n4+255)/256), 256, 0, stream>>>(in, out, n4);
  };
  cvt(wih_l0f, wb_l0f, 2048*512);
  cvt(wih_l0b, wb_l0b, 2048*512);
  cvt(wih_l1f, wb_l1f, 2048*1024);
  cvt(wih_l1b, wb_l1b, 2048*1024);
  cvt(fc_w,    wb_fc,  512*1024);

  // w_hh i8 quant (global scale per matrix) -- 4 matrices per launch
  maxabs4_kernel<<<dim3(64,4), 256, 0, stream>>>(whh_l0f, whh_l0b, whh_l1f, whh_l1b, maxu, 2048*512);
  quantw4_kernel<<<dim3((2048*512/4+255)/256,4), 256, 0, stream>>>(
      whh_l0f, whh_l0b, whh_l1f, whh_l1b, maxu, w8_l0f, w8_l0b, w8_l1f, w8_l1b, 2048*512/4);

  transpose_kernel<<<dim3(19,16,16), 256, 0, stream>>>(x, xt);

  // layer 0: input projections then recurrence
  gemm_bt<u16><<<dim3(75,16), 256, 0, stream>>>(xt, wb_l0f, b_l0f, xpf, NROW, 2048, 512);
  gemm_bt<u16><<<dim3(75,16), 256, 0, stream>>>(xt, wb_l0b, b_l0b, xpb, NROW, 2048, 512);
  lstm_rec12<<<dim3(32), 512, 0, stream>>>(xpf, xpb, w8_l0f, w8_l0b, maxu+0, h0, dpl0, tags0);

  // layer 1
  gemm_bt<u16><<<dim3(75,16), 256, 0, stream>>>(h0, wb_l1f, b_l1f, xpf, NROW, 2048, 1024);
  gemm_bt<u16><<<dim3(75,16), 256, 0, stream>>>(h0, wb_l1b, b_l1b, xpb, NROW, 2048, 1024);
  lstm_rec12<<<dim3(32), 512, 0, stream>>>(xpf, xpb, w8_l1f, w8_l1b, maxu+2, h1, dpl1, tags1);

  // FC + LayerNorm + ReLU
  gemm_bt<float><<<dim3(75,4), 256, 0, stream>>>(h1, wb_fc, fc_b, fco, NROW, 512, 1024);
  ln_relu_kernel<<<dim3(NROW), 256, 0, stream>>>(fco, ln_w, ln_b, outp);
}